// Round 12
// baseline (227.267 us; speedup 1.0000x reference)
//
#include <hip/hip_runtime.h>

#define B_SZ   16
#define SEQ    2048
#define VOCAB  50257
#define EMBED  128
#define DSTATE 16
#define HID    256
#define NCLS   10
#define NEDGE  8192
#define KTR    64          // scan truncation: A<=0.55 -> A^64 < 2e-17
#define LN_EPS 1e-5f
#define NROW   (B_SZ*SEQ)  // 32768
#define BCAP   32          // bucket capacity per dst (Poisson lambda=4)
#define OVCAP  1024        // overflow fallback capacity

// k_prep phase block ranges
#define PB_CAST   4096                  // NROW*32/256
#define PB_BUCKET (PB_CAST + 512)       // B_SZ*NEDGE/256 = 512
#define PB_PRECM  (PB_BUCKET + 128)     // 256 hp, 2 per block
#define PB_CTAB   (PB_PRECM + 16)       // 16 d
#define PB_TOTAL  (PB_CTAB + 1)         // +1 precB

typedef float  f32x4 __attribute__((ext_vector_type(4)));
typedef short  s16x8 __attribute__((ext_vector_type(8)));

__device__ __forceinline__ float scrub(float x){
  return (x == x && fabsf(x) < 1e30f) ? x : 0.f;
}
// fp32 -> bf16 bits, round-to-nearest-even
__device__ __forceinline__ short f2b(float f){
  unsigned int u = __float_as_uint(f);
  unsigned int r = (u + 0x7fffu + ((u >> 16) & 1u)) >> 16;
  return (short)r;
}
__device__ __forceinline__ unsigned int pack2(float a, float b){
  return (unsigned int)(unsigned short)f2b(a)
       | ((unsigned int)(unsigned short)f2b(b) << 16);
}
__device__ __forceinline__ float lo2f(unsigned int v){ return __uint_as_float(v << 16); }
__device__ __forceinline__ float hi2f(unsigned int v){ return __uint_as_float(v & 0xffff0000u); }

// ---------------------------------------------------------------------------
// Heterogeneous prep kernel: all phases mutually independent. (round-10)
__global__ __launch_bounds__(256) void k_prep(
    const int* __restrict__ tokens, const float* __restrict__ emb,
    const float* __restrict__ A_log, const float* __restrict__ B_w,
    const float* __restrict__ Wmsg, const float* __restrict__ Wupd,
    const int* __restrict__ edges,
    float* __restrict__ c_tab, short* __restrict__ Bf, float* __restrict__ MT,
    unsigned int* __restrict__ x_bf, int* __restrict__ cnt,
    unsigned short* __restrict__ bucket, int* __restrict__ ovf_cnt,
    int* __restrict__ ovf){
  int bid = blockIdx.x, tid = threadIdx.x;
  if (bid < PB_CAST){                            // ---- cast: 1,048,576 thr
    int gid = bid*256 + tid;
    int row = gid >> 5, ch = gid & 31;
    int tok = tokens[row];
    tok = tok < 0 ? 0 : (tok >= VOCAB ? VOCAB-1 : tok);
    float4 v = *(const float4*)(emb + (size_t)tok*EMBED + ch*4);
    uint2 o; o.x = pack2(v.x, v.y); o.y = pack2(v.z, v.w);
    *(uint2*)(x_bf + (size_t)row*(EMBED/2) + ch*2) = o;
  } else if (bid < PB_BUCKET){                   // ---- bucket: 131,072 thr
    int eid = (bid-PB_CAST)*256 + tid;
    int b = eid >> 13, i = eid & (NEDGE-1);
    const int* ei = edges + (size_t)b*2*NEDGE;
    int s = ei[i]         & (SEQ-1);
    int d = ei[NEDGE + i] & (SEQ-1);
    int gdst = (b << 11) | d;
    int slot = atomicAdd(&cnt[gdst], 1);
    if (slot < BCAP) bucket[(size_t)gdst*BCAP + slot] = (unsigned short)s;
    else {
      int o = atomicAdd(ovf_cnt, 1);
      if (o < OVCAP) ovf[o] = ((b << 11) | s) | (gdst << 16);
    }
  } else if (bid < PB_PRECM){                    // ---- precM: 2 hp per block
    int hp = (bid-PB_BUCKET)*2 + (tid >> 7);
    int e  = tid & 127;
    const float* w2 = Wupd + (size_t)hp*384 + 128;
    float acc = 0.f;
    for (int h1 = 0; h1 < HID; ++h1)
      acc += Wmsg[h1*EMBED + e] * w2[h1];
    MT[(size_t)hp*EMBED + e] = scrub(acc);
  } else if (bid < PB_CTAB){                     // ---- ctab (wave 0 only)
    if (tid < 64){
      int d = bid - PB_PRECM, lane = tid;
      float a0 = scrub(expf(-expf(A_log[(2*lane+0)*DSTATE + d])));
      float a1 = scrub(expf(-expf(A_log[(2*lane+1)*DSTATE + d])));
      float p0 = 1.f, p1 = 1.f;
      for (int k = 0; k < KTR; ++k){
        float s = p0 + p1;
        for (int off = 32; off; off >>= 1) s += __shfl_down(s, off);
        if (lane == 0) c_tab[k*DSTATE + d] = scrub(s * (1.0f/128.0f));
        p0 *= a0; p1 *= a1;
      }
    }
  } else {                                       // ---- precB (256 slots)
    int idx = tid;
    int c = idx >> 6, lane = idx & 63;
    int n = lane & 15;
    int kb = c*32 + (lane >> 4)*8;
    short v[8];
    #pragma unroll
    for (int jj = 0; jj < 8; ++jj) v[jj] = f2b(B_w[(size_t)n*EMBED + kb + jj]);
    *(s16x8*)(Bf + (size_t)idx*8) = *(s16x8*)v;
  }
}

// ---------------------------------------------------------------------------
// Fused bproj(MFMA) + conv + ssm + LayerNorm; b,m only in LDS. (round-10)
__global__ __launch_bounds__(256) void k_ssm_fused(
    const short* __restrict__ x_bf, const float* __restrict__ c_tab,
    const float* __restrict__ C_w, const float* __restrict__ D_skip,
    const float* __restrict__ ln_g, const float* __restrict__ ln_b,
    const short* __restrict__ Bf, const float* __restrict__ Wupd,
    const float* __restrict__ MT, unsigned int* __restrict__ h_out,
    short* __restrict__ Wcs){
  __shared__ float bsh[128][18];
  __shared__ float msh[64][18];
  __shared__ float Ct[DSTATE][EMBED+2];
  __shared__ float csh[KTR][DSTATE];
  int bid = blockIdx.x, tid = threadIdx.x;

  if (bid >= 512){                      // ---- precW rider blocks
    int idx = (bid-512)*256 + tid;
    int c    = idx >> 10;
    int rem  = idx & 1023;
    int j    = rem >> 6;
    int lane = rem & 63;
    int n  = j*16 + (lane & 15);
    int kb = c*32 + (lane >> 4)*8;
    short v[8];
    #pragma unroll
    for (int jj = 0; jj < 8; ++jj){
      int k = kb + jj;
      float val = (k < 128) ? Wupd[(size_t)n*384 + k] : MT[(size_t)n*EMBED + (k-128)];
      v[jj] = f2b(val);
    }
    *(s16x8*)(Wcs + (size_t)idx*8) = *(s16x8*)v;
    return;
  }

  int b  = bid >> 5;
  int t0 = (bid & 31) * 64;
  for (int i = tid; i < DSTATE*EMBED; i += 256){
    int e = i >> 4, d = i & 15;
    Ct[d][e] = C_w[i];
  }
  for (int i = tid; i < KTR*DSTATE; i += 256)
    csh[i >> 4][i & 15] = c_tab[i];

  int wv = tid >> 6, lane = tid & 63;
  int m = lane & 15, lg = lane >> 4;

  const s16x8* Bp = (const s16x8*)Bf;
  #pragma unroll
  for (int tt = 0; tt < 2; ++tt){
    int tile = wv*2 + tt;
    int trow = t0 - 64 + tile*16;
    f32x4 acc = (f32x4){0.f,0.f,0.f,0.f};
    if (trow >= 0){
      const short* xrow = x_bf + ((size_t)(b*SEQ + trow + m))*EMBED + lg*8;
      #pragma unroll
      for (int c = 0; c < 4; ++c){
        s16x8 a = *(const s16x8*)(xrow + c*32);
        acc = __builtin_amdgcn_mfma_f32_16x16x32_bf16(a, Bp[c*64 + lane], acc, 0, 0, 0);
      }
    }
    #pragma unroll
    for (int r = 0; r < 4; ++r)
      bsh[tile*16 + lg*4 + r][m] = scrub(acc[r]);
  }
  __syncthreads();

  {
    int d = tid & 15;
    #pragma unroll
    for (int it = 0; it < 4; ++it){
      int q = (tid + it*256) >> 4;
      int t = t0 + q;
      int base = 64 + q;
      int kmax = (t+1 < KTR) ? t+1 : KTR;
      float acc = 0.f;
      for (int k = 0; k < kmax; ++k) acc += csh[k][d] * bsh[base-k][d];
      msh[q][d] = scrub(acc);
    }
  }
  __syncthreads();

  int e0 = lane*2;
  float2 dsk = *(const float2*)&D_skip[e0];
  float2 lgv = *(const float2*)&ln_g[e0];
  float2 lbv = *(const float2*)&ln_b[e0];
  const unsigned int* xb = (const unsigned int*)x_bf;
  for (int q = wv*16; q < wv*16+16; ++q){
    int row = b*SEQ + t0 + q;
    unsigned int xp = xb[(size_t)row*(EMBED/2) + lane];
    float x0 = lo2f(xp), x1 = hi2f(xp);
    float y0 = dsk.x*x0, y1 = dsk.y*x1;
    #pragma unroll
    for (int d = 0; d < DSTATE; ++d){
      float md = msh[q][d];
      y0 += md * Ct[d][e0];
      y1 += md * Ct[d][e0+1];
    }
    y0 = scrub(y0); y1 = scrub(y1);
    float s = y0+y1, s2 = y0*y0 + y1*y1;
    for (int off = 32; off; off >>= 1){ s += __shfl_down(s,off); s2 += __shfl_down(s2,off); }
    s = __shfl(s, 0); s2 = __shfl(s2, 0);
    float mu  = s * (1.f/EMBED);
    float var = s2 * (1.f/EMBED) - mu*mu;
    float inv = rsqrtf(fmaxf(var, 0.f) + LN_EPS);
    float o0 = scrub(lgv.x*(y0-mu)*inv + lbv.x);
    float o1 = scrub(lgv.y*(y1-mu)*inv + lbv.y);
    h_out[(size_t)row*(EMBED/2) + lane] = pack2(o0, o1);
  }
}

// ---------------------------------------------------------------------------
// g[gdst][:] = sum over bucketed srcs of h[b*SEQ+src][:]. One wave per dst row
// (fully coalesced 256 B row reads). Round-10 version — measured good.
__global__ __launch_bounds__(256) void k_gather(
    const int* __restrict__ cnt, const unsigned short* __restrict__ bucket,
    const int* __restrict__ ovf_cnt, const int* __restrict__ ovf,
    const unsigned int* __restrict__ h, unsigned int* __restrict__ g){
  int wv = threadIdx.x >> 6, lane = threadIdx.x & 63;
  int gdst = blockIdx.x*4 + wv;
  int n = cnt[gdst]; n = n > BCAP ? BCAP : n;
  int b = gdst >> 11;
  const unsigned int* hb = h + (size_t)b*SEQ*(EMBED/2);
  const unsigned short* bk = bucket + (size_t)gdst*BCAP;
  float ax = 0.f, ay = 0.f;
  for (int i = 0; i < n; ++i){
    unsigned int v = hb[(size_t)bk[i]*(EMBED/2) + lane];
    ax += lo2f(v); ay += hi2f(v);
  }
  int on = *ovf_cnt; on = on > OVCAP ? OVCAP : on;   // ~always 0
  for (int idx = 0; idx < on; ++idx){
    int pk = ovf[idx];
    if (((pk >> 16) & 0x7fff) == gdst){
      unsigned int v = h[(size_t)(pk & 0xffff)*(EMBED/2) + lane];
      ax += lo2f(v); ay += hi2f(v);
    }
  }
  g[(size_t)gdst*(EMBED/2) + lane] = pack2(scrub(ax), scrub(ay));
}

// ---------------------------------------------------------------------------
// MFMA upd+relu+pool (barrier-free main body) + folded classifier tail:
// last block (done-counter) computes out = pool/SEQ . cls_w^T + cls_b.
__global__ __launch_bounds__(256) void k_upd_mfma(
    const short* __restrict__ h, const short* __restrict__ g,
    const short* __restrict__ Wcs, const float* __restrict__ Wupd_b,
    float* __restrict__ pool, const float* __restrict__ cls_w,
    const float* __restrict__ cls_b, float* __restrict__ out,
    int* __restrict__ done){
  __shared__ float psh[B_SZ*HID];    // 16 KB (last block only)
  __shared__ int lastf;
  int tid = threadIdx.x;
  int wave = blockIdx.x*4 + (tid >> 6);
  int lane = tid & 63;
  int row0 = wave * 16;
  int b = row0 >> 11;                      // / SEQ
  int m = lane & 15, lg = lane >> 4;
  const short* hrow = h + (size_t)(row0+m)*EMBED + lg*8;
  const short* grow = g + (size_t)(row0+m)*EMBED + lg*8;

  f32x4 acc[16];
  #pragma unroll
  for (int j = 0; j < 16; ++j) acc[j] = (f32x4){0.f,0.f,0.f,0.f};

  const s16x8* Bp = (const s16x8*)Wcs;
  #pragma unroll
  for (int c = 0; c < 8; ++c){
    s16x8 a = (c < 4) ? *(const s16x8*)(hrow + c*32)
                      : *(const s16x8*)(grow + (c-4)*32);
    #pragma unroll
    for (int j = 0; j < 16; ++j){
      s16x8 bfr = Bp[(c*16 + j)*64 + lane];
      acc[j] = __builtin_amdgcn_mfma_f32_16x16x32_bf16(a, bfr, acc[j], 0, 0, 0);
    }
  }

  // C/D layout: col = lane&15, row = (lane>>4)*4 + reg
  #pragma unroll
  for (int j = 0; j < 16; ++j){
    int n = j*16 + (lane & 15);
    float bias = Wupd_b[n];
    float v = 0.f;
    #pragma unroll
    for (int r = 0; r < 4; ++r) v += fmaxf(acc[j][r] + bias, 0.f);
    v += __shfl_down(v, 32);
    v += __shfl_down(v, 16);
    if (lane < 16) atomicAdd(&pool[b*HID + n], scrub(v));
  }

  // ---- completion counter; last block computes the classifier
  __threadfence();
  __syncthreads();
  if (tid == 0) lastf = (atomicAdd(done, 1) == (int)gridDim.x - 1) ? 1 : 0;
  __syncthreads();
  if (!lastf) return;
  __threadfence();
  for (int i = tid; i < B_SZ*HID; i += 256)
    psh[i] = atomicAdd(&pool[i], 0.0f);        // coherent read via atomic path
  __syncthreads();
  if (tid < B_SZ*NCLS){
    int bb = tid / NCLS, cc = tid - bb*NCLS;
    const float* p = psh + bb*HID;
    const float* w = cls_w + cc*HID;
    float s = 0.f;
    for (int h1 = 0; h1 < HID; ++h1) s += p[h1]*w[h1];
    out[tid] = scrub(s * (1.0f/SEQ) + cls_b[cc]);
  }
}

// ---------------------------------------------------------------------------
extern "C" void kernel_launch(void* const* d_in, const int* in_sizes, int n_in,
                              void* d_out, int out_size, void* d_ws, size_t ws_size,
                              hipStream_t stream) {
  const int*   tokens = (const int*)d_in[0];
  const int*   edges  = (const int*)d_in[2];
  const float* emb    = (const float*)d_in[3];
  const float* A_log  = (const float*)d_in[4];
  const float* B_w    = (const float*)d_in[5];
  const float* C_w    = (const float*)d_in[6];
  const float* D_skip = (const float*)d_in[7];
  const float* ln_g   = (const float*)d_in[8];
  const float* ln_b   = (const float*)d_in[9];
  const float* Wmsg   = (const float*)d_in[10];
  const float* Wupd   = (const float*)d_in[11];
  const float* Wupd_b = (const float*)d_in[12];
  const float* cls_w  = (const float*)d_in[13];
  const float* cls_b  = (const float*)d_in[14];
  float* out = (float*)d_out;

  // workspace layout (~26.5 MB)
  char* ws = (char*)d_ws;
  float* c_tab = (float*)ws;  ws += 16*1024;                 // 4 KB used
  float* MT    = (float*)ws;  ws += (size_t)HID*EMBED*4;     // 128 KB
  short* Wcs   = (short*)ws;  ws += (size_t)HID*HID*2;       // 128 KB
  short* Bf    = (short*)ws;  ws += 16*1024;                 // 4 KB used
  char*  zbase = ws;
  float* pool  = (float*)ws;  ws += (size_t)B_SZ*HID*4;      // 16 KB
  int*   cnt   = (int*)ws;    ws += (size_t)NROW*4;          // 128 KB
  int*   ovf_cnt = (int*)ws;  ws += 64;
  int*   ovf   = (int*)ws;    ws += OVCAP*4;                 // 4 KB
  int*   done  = (int*)ws;    ws += 64;
  size_t zlen = (size_t)((char*)ws - zbase);
  unsigned short* bucket = (unsigned short*)ws; ws += (size_t)NROW*BCAP*2; // 2 MB
  short* x_bf  = (short*)ws;  ws += (size_t)NROW*EMBED*2;    // 8 MB
  short* h_bf  = (short*)ws;  ws += (size_t)NROW*EMBED*2;    // 8 MB
  short* g_bf  = (short*)ws;  ws += (size_t)NROW*EMBED*2;    // 8 MB

  hipMemsetAsync(zbase, 0, zlen, stream);
  hipLaunchKernelGGL(k_prep, dim3(PB_TOTAL), dim3(256), 0, stream,
                     tokens, emb, A_log, B_w, Wmsg, Wupd, edges,
                     c_tab, Bf, MT, (unsigned int*)x_bf, cnt, bucket, ovf_cnt, ovf);
  hipLaunchKernelGGL(k_ssm_fused, dim3(544), dim3(256), 0, stream,
                     x_bf, c_tab, C_w, D_skip, ln_g, ln_b, Bf, Wupd, MT,
                     (unsigned int*)h_bf, Wcs);
  hipLaunchKernelGGL(k_gather, dim3(NROW/4), dim3(256), 0, stream,
                     cnt, bucket, ovf_cnt, ovf, (const unsigned int*)h_bf,
                     (unsigned int*)g_bf);
  hipLaunchKernelGGL(k_upd_mfma, dim3(NROW/64), dim3(256), 0, stream,
                     h_bf, g_bf, Wcs, Wupd_b, pool, cls_w, cls_b, out, done);
}

// Round 13
// 194.352 us; speedup vs baseline: 1.1694x; 1.1694x over previous
//
#include <hip/hip_runtime.h>

#define B_SZ   16
#define SEQ    2048
#define VOCAB  50257
#define EMBED  128
#define DSTATE 16
#define HID    256
#define NCLS   10
#define NEDGE  8192
#define KTR    64          // scan truncation: A<=0.55 -> A^64 < 2e-17
#define LN_EPS 1e-5f
#define NROW   (B_SZ*SEQ)  // 32768
#define BCAP   32          // bucket capacity per dst (Poisson lambda=4)
#define OVCAP  1024        // overflow fallback capacity

// k_prep phase block ranges
#define PB_CAST   4096                  // NROW*32/256
#define PB_BUCKET (PB_CAST + 512)       // B_SZ*NEDGE/256 = 512
#define PB_PRECM  (PB_BUCKET + 128)     // 256 hp, 2 per block
#define PB_CTAB   (PB_PRECM + 16)       // 16 d
#define PB_PRECB  (PB_CTAB + 1)         // 1 block
#define PB_TOTAL  (PB_PRECB + 1)        // +1 out-init (cls_b)

typedef float  f32x4 __attribute__((ext_vector_type(4)));
typedef short  s16x8 __attribute__((ext_vector_type(8)));

__device__ __forceinline__ float scrub(float x){
  return (x == x && fabsf(x) < 1e30f) ? x : 0.f;
}
// fp32 -> bf16 bits, round-to-nearest-even
__device__ __forceinline__ short f2b(float f){
  unsigned int u = __float_as_uint(f);
  unsigned int r = (u + 0x7fffu + ((u >> 16) & 1u)) >> 16;
  return (short)r;
}
__device__ __forceinline__ unsigned int pack2(float a, float b){
  return (unsigned int)(unsigned short)f2b(a)
       | ((unsigned int)(unsigned short)f2b(b) << 16);
}
__device__ __forceinline__ float lo2f(unsigned int v){ return __uint_as_float(v << 16); }
__device__ __forceinline__ float hi2f(unsigned int v){ return __uint_as_float(v & 0xffff0000u); }

// ---------------------------------------------------------------------------
// Heterogeneous prep kernel: all phases mutually independent.
__global__ __launch_bounds__(256) void k_prep(
    const int* __restrict__ tokens, const float* __restrict__ emb,
    const float* __restrict__ A_log, const float* __restrict__ B_w,
    const float* __restrict__ Wmsg, const float* __restrict__ Wupd,
    const int* __restrict__ edges, const float* __restrict__ cls_b,
    float* __restrict__ c_tab, short* __restrict__ Bf, float* __restrict__ MT,
    unsigned int* __restrict__ x_bf, int* __restrict__ cnt,
    unsigned short* __restrict__ bucket, int* __restrict__ ovf_cnt,
    int* __restrict__ ovf, float* __restrict__ out){
  int bid = blockIdx.x, tid = threadIdx.x;
  if (bid < PB_CAST){                            // ---- cast: 1,048,576 thr
    int gid = bid*256 + tid;
    int row = gid >> 5, ch = gid & 31;
    int tok = tokens[row];
    tok = tok < 0 ? 0 : (tok >= VOCAB ? VOCAB-1 : tok);
    float4 v = *(const float4*)(emb + (size_t)tok*EMBED + ch*4);
    uint2 o; o.x = pack2(v.x, v.y); o.y = pack2(v.z, v.w);
    *(uint2*)(x_bf + (size_t)row*(EMBED/2) + ch*2) = o;
  } else if (bid < PB_BUCKET){                   // ---- bucket: 131,072 thr
    int eid = (bid-PB_CAST)*256 + tid;
    int b = eid >> 13, i = eid & (NEDGE-1);
    const int* ei = edges + (size_t)b*2*NEDGE;
    int s = ei[i]         & (SEQ-1);
    int d = ei[NEDGE + i] & (SEQ-1);
    int gdst = (b << 11) | d;
    int slot = atomicAdd(&cnt[gdst], 1);
    if (slot < BCAP) bucket[(size_t)gdst*BCAP + slot] = (unsigned short)s;
    else {
      int o = atomicAdd(ovf_cnt, 1);
      if (o < OVCAP) ovf[o] = ((b << 11) | s) | (gdst << 16);
    }
  } else if (bid < PB_PRECM){                    // ---- precM: 2 hp per block
    int hp = (bid-PB_BUCKET)*2 + (tid >> 7);
    int e  = tid & 127;
    const float* w2 = Wupd + (size_t)hp*384 + 128;
    float acc = 0.f;
    for (int h1 = 0; h1 < HID; ++h1)
      acc += Wmsg[h1*EMBED + e] * w2[h1];
    MT[(size_t)hp*EMBED + e] = scrub(acc);
  } else if (bid < PB_CTAB){                     // ---- ctab (wave 0 only)
    if (tid < 64){
      int d = bid - PB_PRECM, lane = tid;
      float a0 = scrub(expf(-expf(A_log[(2*lane+0)*DSTATE + d])));
      float a1 = scrub(expf(-expf(A_log[(2*lane+1)*DSTATE + d])));
      float p0 = 1.f, p1 = 1.f;
      for (int k = 0; k < KTR; ++k){
        float s = p0 + p1;
        for (int off = 32; off; off >>= 1) s += __shfl_down(s, off);
        if (lane == 0) c_tab[k*DSTATE + d] = scrub(s * (1.0f/128.0f));
        p0 *= a0; p1 *= a1;
      }
    }
  } else if (bid < PB_PRECB){                    // ---- precB (256 slots)
    int idx = tid;
    int c = idx >> 6, lane = idx & 63;
    int n = lane & 15;
    int kb = c*32 + (lane >> 4)*8;
    short v[8];
    #pragma unroll
    for (int jj = 0; jj < 8; ++jj) v[jj] = f2b(B_w[(size_t)n*EMBED + kb + jj]);
    *(s16x8*)(Bf + (size_t)idx*8) = *(s16x8*)v;
  } else {                                       // ---- out init = cls_b
    if (tid < B_SZ*NCLS) out[tid] = cls_b[tid % NCLS];
  }
}

// ---------------------------------------------------------------------------
// Fused bproj(MFMA) + conv + ssm + LayerNorm; b,m only in LDS. (round-10)
__global__ __launch_bounds__(256) void k_ssm_fused(
    const short* __restrict__ x_bf, const float* __restrict__ c_tab,
    const float* __restrict__ C_w, const float* __restrict__ D_skip,
    const float* __restrict__ ln_g, const float* __restrict__ ln_b,
    const short* __restrict__ Bf, const float* __restrict__ Wupd,
    const float* __restrict__ MT, unsigned int* __restrict__ h_out,
    short* __restrict__ Wcs){
  __shared__ float bsh[128][18];
  __shared__ float msh[64][18];
  __shared__ float Ct[DSTATE][EMBED+2];
  __shared__ float csh[KTR][DSTATE];
  int bid = blockIdx.x, tid = threadIdx.x;

  if (bid >= 512){                      // ---- precW rider blocks
    int idx = (bid-512)*256 + tid;
    int c    = idx >> 10;
    int rem  = idx & 1023;
    int j    = rem >> 6;
    int lane = rem & 63;
    int n  = j*16 + (lane & 15);
    int kb = c*32 + (lane >> 4)*8;
    short v[8];
    #pragma unroll
    for (int jj = 0; jj < 8; ++jj){
      int k = kb + jj;
      float val = (k < 128) ? Wupd[(size_t)n*384 + k] : MT[(size_t)n*EMBED + (k-128)];
      v[jj] = f2b(val);
    }
    *(s16x8*)(Wcs + (size_t)idx*8) = *(s16x8*)v;
    return;
  }

  int b  = bid >> 5;
  int t0 = (bid & 31) * 64;
  for (int i = tid; i < DSTATE*EMBED; i += 256){
    int e = i >> 4, d = i & 15;
    Ct[d][e] = C_w[i];
  }
  for (int i = tid; i < KTR*DSTATE; i += 256)
    csh[i >> 4][i & 15] = c_tab[i];

  int wv = tid >> 6, lane = tid & 63;
  int m = lane & 15, lg = lane >> 4;

  const s16x8* Bp = (const s16x8*)Bf;
  #pragma unroll
  for (int tt = 0; tt < 2; ++tt){
    int tile = wv*2 + tt;
    int trow = t0 - 64 + tile*16;
    f32x4 acc = (f32x4){0.f,0.f,0.f,0.f};
    if (trow >= 0){
      const short* xrow = x_bf + ((size_t)(b*SEQ + trow + m))*EMBED + lg*8;
      #pragma unroll
      for (int c = 0; c < 4; ++c){
        s16x8 a = *(const s16x8*)(xrow + c*32);
        acc = __builtin_amdgcn_mfma_f32_16x16x32_bf16(a, Bp[c*64 + lane], acc, 0, 0, 0);
      }
    }
    #pragma unroll
    for (int r = 0; r < 4; ++r)
      bsh[tile*16 + lg*4 + r][m] = scrub(acc[r]);
  }
  __syncthreads();

  {
    int d = tid & 15;
    #pragma unroll
    for (int it = 0; it < 4; ++it){
      int q = (tid + it*256) >> 4;
      int t = t0 + q;
      int base = 64 + q;
      int kmax = (t+1 < KTR) ? t+1 : KTR;
      float acc = 0.f;
      for (int k = 0; k < kmax; ++k) acc += csh[k][d] * bsh[base-k][d];
      msh[q][d] = scrub(acc);
    }
  }
  __syncthreads();

  int e0 = lane*2;
  float2 dsk = *(const float2*)&D_skip[e0];
  float2 lgv = *(const float2*)&ln_g[e0];
  float2 lbv = *(const float2*)&ln_b[e0];
  const unsigned int* xb = (const unsigned int*)x_bf;
  for (int q = wv*16; q < wv*16+16; ++q){
    int row = b*SEQ + t0 + q;
    unsigned int xp = xb[(size_t)row*(EMBED/2) + lane];
    float x0 = lo2f(xp), x1 = hi2f(xp);
    float y0 = dsk.x*x0, y1 = dsk.y*x1;
    #pragma unroll
    for (int d = 0; d < DSTATE; ++d){
      float md = msh[q][d];
      y0 += md * Ct[d][e0];
      y1 += md * Ct[d][e0+1];
    }
    y0 = scrub(y0); y1 = scrub(y1);
    float s = y0+y1, s2 = y0*y0 + y1*y1;
    for (int off = 32; off; off >>= 1){ s += __shfl_down(s,off); s2 += __shfl_down(s2,off); }
    s = __shfl(s, 0); s2 = __shfl(s2, 0);
    float mu  = s * (1.f/EMBED);
    float var = s2 * (1.f/EMBED) - mu*mu;
    float inv = rsqrtf(fmaxf(var, 0.f) + LN_EPS);
    float o0 = scrub(lgv.x*(y0-mu)*inv + lbv.x);
    float o1 = scrub(lgv.y*(y1-mu)*inv + lbv.y);
    h_out[(size_t)row*(EMBED/2) + lane] = pack2(o0, o1);
  }
}

// ---------------------------------------------------------------------------
// g[gdst][:] = sum over bucketed srcs of h[b*SEQ+src][:]. One wave per dst row
// (fully coalesced 256 B row reads). Round-10 version — measured good.
__global__ __launch_bounds__(256) void k_gather(
    const int* __restrict__ cnt, const unsigned short* __restrict__ bucket,
    const int* __restrict__ ovf_cnt, const int* __restrict__ ovf,
    const unsigned int* __restrict__ h, unsigned int* __restrict__ g){
  int wv = threadIdx.x >> 6, lane = threadIdx.x & 63;
  int gdst = blockIdx.x*4 + wv;
  int n = cnt[gdst]; n = n > BCAP ? BCAP : n;
  int b = gdst >> 11;
  const unsigned int* hb = h + (size_t)b*SEQ*(EMBED/2);
  const unsigned short* bk = bucket + (size_t)gdst*BCAP;
  float ax = 0.f, ay = 0.f;
  for (int i = 0; i < n; ++i){
    unsigned int v = hb[(size_t)bk[i]*(EMBED/2) + lane];
    ax += lo2f(v); ay += hi2f(v);
  }
  int on = *ovf_cnt; on = on > OVCAP ? OVCAP : on;   // ~always 0
  for (int idx = 0; idx < on; ++idx){
    int pk = ovf[idx];
    if (((pk >> 16) & 0x7fff) == gdst){
      unsigned int v = h[(size_t)(pk & 0xffff)*(EMBED/2) + lane];
      ax += lo2f(v); ay += hi2f(v);
    }
  }
  g[(size_t)gdst*(EMBED/2) + lane] = pack2(scrub(ax), scrub(ay));
}

// ---------------------------------------------------------------------------
// MFMA upd+relu + G12 epilogue: per-wave column sums -> LDS -> block reduce ->
// classifier dots in-block -> 10 atomics to out. No pool, no fence, no k_cls.
__global__ __launch_bounds__(256) void k_upd_mfma(
    const short* __restrict__ h, const short* __restrict__ g,
    const short* __restrict__ Wcs, const float* __restrict__ Wupd_b,
    const float* __restrict__ cls_w, float* __restrict__ out){
  __shared__ float psum[4*HID];      // 4 KB: per-wave column sums
  __shared__ float clsw[NCLS*HID];   // 10 KB
  int tid = threadIdx.x;
  int wave = blockIdx.x*4 + (tid >> 6);
  int lane = tid & 63;
  int row0 = wave * 16;
  int b = (blockIdx.x*64) >> 11;           // block's batch (64 | 2048)
  int m = lane & 15, lg = lane >> 4;
  const short* hrow = h + (size_t)(row0+m)*EMBED + lg*8;
  const short* grow = g + (size_t)(row0+m)*EMBED + lg*8;

  for (int i = tid; i < NCLS*HID; i += 256) clsw[i] = cls_w[i];

  f32x4 acc[16];
  #pragma unroll
  for (int j = 0; j < 16; ++j) acc[j] = (f32x4){0.f,0.f,0.f,0.f};

  const s16x8* Bp = (const s16x8*)Wcs;
  #pragma unroll
  for (int c = 0; c < 8; ++c){
    s16x8 a = (c < 4) ? *(const s16x8*)(hrow + c*32)
                      : *(const s16x8*)(grow + (c-4)*32);
    #pragma unroll
    for (int j = 0; j < 16; ++j){
      s16x8 bfr = Bp[(c*16 + j)*64 + lane];
      acc[j] = __builtin_amdgcn_mfma_f32_16x16x32_bf16(a, bfr, acc[j], 0, 0, 0);
    }
  }

  // per-wave column sums (C/D layout: col = lane&15, row = lg*4 + reg)
  int wv = tid >> 6;
  #pragma unroll
  for (int j = 0; j < 16; ++j){
    int n = j*16 + (lane & 15);
    float bias = Wupd_b[n];
    float v = 0.f;
    #pragma unroll
    for (int r = 0; r < 4; ++r) v += fmaxf(acc[j][r] + bias, 0.f);
    v += __shfl_down(v, 32);
    v += __shfl_down(v, 16);
    if (lane < 16) psum[wv*HID + n] = scrub(v);
  }
  __syncthreads();
  // block reduce: thread t owns column t (each loc in [0,256) is read/written
  // by the same thread only)
  float bp = psum[tid] + psum[HID+tid] + psum[2*HID+tid] + psum[3*HID+tid];
  psum[tid] = bp;
  __syncthreads();
  // wave 0: 10 classifier dots of length 256 from LDS, one atomic each
  if (tid < 64){
    for (int c = 0; c < NCLS; ++c){
      float s = 0.f;
      #pragma unroll
      for (int k = 0; k < 4; ++k)
        s += psum[tid + k*64] * clsw[c*HID + tid + k*64];
      for (int off = 32; off; off >>= 1) s += __shfl_down(s, off);
      if (tid == 0) atomicAdd(&out[b*NCLS + c], scrub(s * (1.0f/SEQ)));
    }
  }
}

// ---------------------------------------------------------------------------
extern "C" void kernel_launch(void* const* d_in, const int* in_sizes, int n_in,
                              void* d_out, int out_size, void* d_ws, size_t ws_size,
                              hipStream_t stream) {
  const int*   tokens = (const int*)d_in[0];
  const int*   edges  = (const int*)d_in[2];
  const float* emb    = (const float*)d_in[3];
  const float* A_log  = (const float*)d_in[4];
  const float* B_w    = (const float*)d_in[5];
  const float* C_w    = (const float*)d_in[6];
  const float* D_skip = (const float*)d_in[7];
  const float* ln_g   = (const float*)d_in[8];
  const float* ln_b   = (const float*)d_in[9];
  const float* Wmsg   = (const float*)d_in[10];
  const float* Wupd   = (const float*)d_in[11];
  const float* Wupd_b = (const float*)d_in[12];
  const float* cls_w  = (const float*)d_in[13];
  const float* cls_b  = (const float*)d_in[14];
  float* out = (float*)d_out;

  // workspace layout (~26.5 MB)
  char* ws = (char*)d_ws;
  float* c_tab = (float*)ws;  ws += 16*1024;                 // 4 KB used
  float* MT    = (float*)ws;  ws += (size_t)HID*EMBED*4;     // 128 KB
  short* Wcs   = (short*)ws;  ws += (size_t)HID*HID*2;       // 128 KB
  short* Bf    = (short*)ws;  ws += 16*1024;                 // 4 KB used
  char*  zbase = ws;
  int*   cnt   = (int*)ws;    ws += (size_t)NROW*4;          // 128 KB
  int*   ovf_cnt = (int*)ws;  ws += 64;
  int*   ovf   = (int*)ws;    ws += OVCAP*4;                 // 4 KB
  size_t zlen = (size_t)((char*)ws - zbase);
  unsigned short* bucket = (unsigned short*)ws; ws += (size_t)NROW*BCAP*2; // 2 MB
  short* x_bf  = (short*)ws;  ws += (size_t)NROW*EMBED*2;    // 8 MB
  short* h_bf  = (short*)ws;  ws += (size_t)NROW*EMBED*2;    // 8 MB
  short* g_bf  = (short*)ws;  ws += (size_t)NROW*EMBED*2;    // 8 MB

  hipMemsetAsync(zbase, 0, zlen, stream);
  hipLaunchKernelGGL(k_prep, dim3(PB_TOTAL), dim3(256), 0, stream,
                     tokens, emb, A_log, B_w, Wmsg, Wupd, edges, cls_b,
                     c_tab, Bf, MT, (unsigned int*)x_bf, cnt, bucket,
                     ovf_cnt, ovf, out);
  hipLaunchKernelGGL(k_ssm_fused, dim3(544), dim3(256), 0, stream,
                     x_bf, c_tab, C_w, D_skip, ln_g, ln_b, Bf, Wupd, MT,
                     (unsigned int*)h_bf, Wcs);
  hipLaunchKernelGGL(k_gather, dim3(NROW/4), dim3(256), 0, stream,
                     cnt, bucket, ovf_cnt, ovf, (const unsigned int*)h_bf,
                     (unsigned int*)g_bf);
  hipLaunchKernelGGL(k_upd_mfma, dim3(NROW/64), dim3(256), 0, stream,
                     h_bf, g_bf, Wcs, Wupd_b, cls_w, out);
}